// Round 1
// baseline (1033.243 us; speedup 1.0000x reference)
//
#include <hip/hip_runtime.h>
#include <hip/hip_bf16.h>
#include <math.h>

// out[n*3] zeroed before this kernel (hipMemsetAsync on stream).
// One thread per edge: compute analytic force, dual scatter via atomics.
__global__ void __launch_bounds__(256)
edge_force_scatter(const float* __restrict__ disp,
                   const float* __restrict__ a,
                   const float* __restrict__ b,
                   const int* __restrict__ src,
                   const int* __restrict__ dst,
                   float* __restrict__ out,
                   int E) {
    int e = blockIdx.x * blockDim.x + threadIdx.x;
    if (e >= E) return;

    float dx = disp[3 * e + 0];
    float dy = disp[3 * e + 1];
    float dz = disp[3 * e + 2];
    float r2 = dx * dx + dy * dy + dz * dz;
    // force = -dE/ddisp = -2*disp*(a - b*exp(-r2))
    float coef = -2.0f * (a[e] - b[e] * expf(-r2));
    float fx = coef * dx, fy = coef * dy, fz = coef * dz;

    int s = src[e];
    int d = dst[e];

    // f_src - f_dst  ==>  +f at src row, -f at dst row
    atomicAdd(&out[3 * s + 0], fx);
    atomicAdd(&out[3 * s + 1], fy);
    atomicAdd(&out[3 * s + 2], fz);
    atomicAdd(&out[3 * d + 0], -fx);
    atomicAdd(&out[3 * d + 1], -fy);
    atomicAdd(&out[3 * d + 2], -fz);
}

extern "C" void kernel_launch(void* const* d_in, const int* in_sizes, int n_in,
                              void* d_out, int out_size, void* d_ws, size_t ws_size,
                              hipStream_t stream) {
    const float* disp = (const float*)d_in[0];   // [E,3]
    const float* a    = (const float*)d_in[1];   // [E]
    const float* b    = (const float*)d_in[2];   // [E]
    const int*   ei   = (const int*)d_in[3];     // [2,E] (int, row-major)
    // d_in[4] = atom_node, only defines N; out_size = 3*N already.

    int E = in_sizes[1];
    float* out = (float*)d_out;

    // Harness poisons d_out with 0xAA before every launch; zero it.
    hipMemsetAsync(d_out, 0, (size_t)out_size * sizeof(float), stream);

    int block = 256;
    int grid = (E + block - 1) / block;
    edge_force_scatter<<<grid, block, 0, stream>>>(disp, a, b, ei, ei + E, out, E);
}

// Round 2
// 1030.307 us; speedup vs baseline: 1.0028x; 1.0028x over previous
//
#include <hip/hip_runtime.h>
#include <hip/hip_bf16.h>
#include <math.h>

#define N_XCD 8

// HW_REG_XCC_ID = 20 on gfx940+; read full reg, mask low bits.
// [measured: learn_hip m09 — returns 0..7 on MI355X]
__device__ __forceinline__ unsigned xcc_id() {
    unsigned v = __builtin_amdgcn_s_getreg(20 | (0 << 6) | (31 << 11));
    return v & (N_XCD - 1);
}

// Per-edge force + scatter into this XCD's private replica using
// workgroup-scope (XCD-L2-local) atomics. Correct because replica r is only
// ever touched from XCD r (hardware XCC_ID), so no cross-XCD coherence needed.
__global__ void __launch_bounds__(256)
edge_force_scatter_xcd(const float* __restrict__ disp,
                       const float* __restrict__ a,
                       const float* __restrict__ b,
                       const int* __restrict__ src,
                       const int* __restrict__ dst,
                       float* __restrict__ ws,   // [N_XCD][out_size]
                       int out_size,
                       int E) {
    int e = blockIdx.x * blockDim.x + threadIdx.x;
    if (e >= E) return;

    float* rep = ws + (size_t)xcc_id() * out_size;

    float dx = disp[3 * e + 0];
    float dy = disp[3 * e + 1];
    float dz = disp[3 * e + 2];
    float r2 = dx * dx + dy * dy + dz * dz;
    // force = -dE/ddisp = -2*disp*(a - b*exp(-r2))
    float coef = -2.0f * (a[e] - b[e] * __expf(-r2));
    float fx = coef * dx, fy = coef * dy, fz = coef * dz;

    int s = 3 * src[e];
    int d = 3 * dst[e];

    __hip_atomic_fetch_add(&rep[s + 0], fx, __ATOMIC_RELAXED, __HIP_MEMORY_SCOPE_WORKGROUP);
    __hip_atomic_fetch_add(&rep[s + 1], fy, __ATOMIC_RELAXED, __HIP_MEMORY_SCOPE_WORKGROUP);
    __hip_atomic_fetch_add(&rep[s + 2], fz, __ATOMIC_RELAXED, __HIP_MEMORY_SCOPE_WORKGROUP);
    __hip_atomic_fetch_add(&rep[d + 0], -fx, __ATOMIC_RELAXED, __HIP_MEMORY_SCOPE_WORKGROUP);
    __hip_atomic_fetch_add(&rep[d + 1], -fy, __ATOMIC_RELAXED, __HIP_MEMORY_SCOPE_WORKGROUP);
    __hip_atomic_fetch_add(&rep[d + 2], -fz, __ATOMIC_RELAXED, __HIP_MEMORY_SCOPE_WORKGROUP);
}

// out[i] = sum over replicas
__global__ void __launch_bounds__(256)
reduce_replicas(const float* __restrict__ ws, float* __restrict__ out, int out_size) {
    int i = blockIdx.x * blockDim.x + threadIdx.x;
    if (i >= out_size) return;
    float acc = 0.0f;
#pragma unroll
    for (int r = 0; r < N_XCD; ++r)
        acc += ws[(size_t)r * out_size + i];
    out[i] = acc;
}

// Fallback (round-1 path) if ws is too small.
__global__ void __launch_bounds__(256)
edge_force_scatter_direct(const float* __restrict__ disp,
                          const float* __restrict__ a,
                          const float* __restrict__ b,
                          const int* __restrict__ src,
                          const int* __restrict__ dst,
                          float* __restrict__ out,
                          int E) {
    int e = blockIdx.x * blockDim.x + threadIdx.x;
    if (e >= E) return;
    float dx = disp[3 * e + 0], dy = disp[3 * e + 1], dz = disp[3 * e + 2];
    float r2 = dx * dx + dy * dy + dz * dz;
    float coef = -2.0f * (a[e] - b[e] * __expf(-r2));
    float fx = coef * dx, fy = coef * dy, fz = coef * dz;
    int s = 3 * src[e], d = 3 * dst[e];
    atomicAdd(&out[s + 0], fx);
    atomicAdd(&out[s + 1], fy);
    atomicAdd(&out[s + 2], fz);
    atomicAdd(&out[d + 0], -fx);
    atomicAdd(&out[d + 1], -fy);
    atomicAdd(&out[d + 2], -fz);
}

extern "C" void kernel_launch(void* const* d_in, const int* in_sizes, int n_in,
                              void* d_out, int out_size, void* d_ws, size_t ws_size,
                              hipStream_t stream) {
    const float* disp = (const float*)d_in[0];   // [E,3]
    const float* a    = (const float*)d_in[1];   // [E]
    const float* b    = (const float*)d_in[2];   // [E]
    const int*   ei   = (const int*)d_in[3];     // [2,E]

    int E = in_sizes[1];
    float* out = (float*)d_out;

    size_t rep_bytes = (size_t)N_XCD * out_size * sizeof(float);
    int block = 256;
    int grid_e = (E + block - 1) / block;

    if (ws_size >= rep_bytes) {
        float* ws = (float*)d_ws;
        hipMemsetAsync(d_ws, 0, rep_bytes, stream);
        edge_force_scatter_xcd<<<grid_e, block, 0, stream>>>(
            disp, a, b, ei, ei + E, ws, out_size, E);
        int grid_r = (out_size + block - 1) / block;
        reduce_replicas<<<grid_r, block, 0, stream>>>(ws, out, out_size);
    } else {
        hipMemsetAsync(d_out, 0, (size_t)out_size * sizeof(float), stream);
        edge_force_scatter_direct<<<grid_e, block, 0, stream>>>(
            disp, a, b, ei, ei + E, out, E);
    }
}